// Round 16
// baseline (901.562 us; speedup 1.0000x reference)
//
#include <hip/hip_runtime.h>
#include <hip/hip_fp16.h>

#define NN 20000   // nodes
#define NP 20032   // padded nodes (313*64)
#define DD 64      // emb dim
#define HH 512     // hidden
#define EE 320000  // edges per graph
#define ATT_BLOCKS 625
#define BLOCKS_E (EE / 256) // 1250
#define CB 313              // coarse buckets (dst>>6), 313*64 >= 20000
#define EPB 4096            // edges per bucket_coarse block
#define B1_BLOCKS ((EE + EPB - 1) / EPB)  // 79
#define ZERO_N (3 * NN + 3 * CB)
#define ZERO_BLOCKS ((ZERO_N + 255) / 256)

typedef __attribute__((ext_vector_type(8))) short short8;
typedef __attribute__((ext_vector_type(4))) float f32x4;

__device__ __forceinline__ ushort f2bf(float f) {
    union { float f; unsigned u; } v; v.f = f;
    unsigned r = v.u + 0x7FFF + ((v.u >> 16) & 1);   // RNE
    return (ushort)(r >> 16);
}
__device__ __forceinline__ float bf2f(ushort h) {
    union { unsigned u; float f; } v; v.u = ((unsigned)h) << 16;
    return v.f;
}
__device__ __forceinline__ float ew_of(uint w) {
    __half h = __ushort_as_half((ushort)(w >> 16));
    return __half2float(h);
}

// ---------------- CSR histogram ----------------
__global__ __launch_bounds__(256) void hist3(const int* __restrict__ d0,
                                             const int* __restrict__ d1,
                                             const int* __restrict__ d2,
                                             int* __restrict__ cnt) {
    int g = blockIdx.x / BLOCKS_E;
    int e = (blockIdx.x % BLOCKS_E) * 256 + threadIdx.x;
    const int* d = (g == 0) ? d0 : (g == 1) ? d1 : d2;
    if (e < EE) atomicAdd(&cnt[g * NN + d[e]], 1);
}

// scan + invd fused: one block per graph
__global__ __launch_bounds__(1024) void scan_kernel(const int* __restrict__ cnt,
                                                    int* __restrict__ rowptr,
                                                    float* __restrict__ invd) {
    __shared__ int part[1024];
    int g = blockIdx.x;
    const int* c = cnt + g * NN;
    int* rp = rowptr + g * (NN + 1);
    int tid = threadIdx.x;
    const int CH = (NN + 1023) / 1024;
    int i0 = tid * CH;
    int s = 0;
    for (int i = 0; i < CH; ++i) { int idx = i0 + i; if (idx < NN) s += c[idx]; }
    part[tid] = s;
    __syncthreads();
    for (int off = 1; off < 1024; off <<= 1) {
        int v = (tid >= off) ? part[tid - off] : 0;
        __syncthreads();
        part[tid] += v;
        __syncthreads();
    }
    int run = (tid > 0) ? part[tid - 1] : 0;
    for (int i = 0; i < CH; ++i) {
        int idx = i0 + i;
        if (idx < NN) {
            int cv = c[idx];
            rp[idx] = run; run += cv;
            invd[g * NN + idx] = 1.0f / fmaxf((float)cv, 1.0f);
        }
    }
    if (tid == 1023) rp[NN] = part[1023];
}

// ---------------- bucket: coarse partition into 64-node windows ----------------
__global__ __launch_bounds__(256) void bucket_coarse(
    const int* __restrict__ s0, const int* __restrict__ d0, const float* __restrict__ w0,
    const int* __restrict__ s1, const int* __restrict__ d1, const float* __restrict__ w1,
    const int* __restrict__ s2, const int* __restrict__ d2,
    const int* __restrict__ rowptr,
    int* __restrict__ ccur,          // [3*CB], zeroed by pack_all
    uint* __restrict__ ce,           // [3*EE] coarse packed {ew_f16<<16 | src}
    ushort* __restrict__ cd) {       // [3*EE] coarse dst
    __shared__ int cnt_s[CB];
    __shared__ int off_s[CB];
    __shared__ int pos_s[CB];
    __shared__ int gbase[CB];
    __shared__ uint lword[EPB];
    __shared__ ushort ldst[EPB];
    int g = blockIdx.x / B1_BLOCKS;
    int blk = blockIdx.x % B1_BLOCKS;
    const int* S = (g == 0) ? s0 : (g == 1) ? s1 : s2;
    const int* D = (g == 0) ? d0 : (g == 1) ? d1 : d2;
    const float* W = (g == 0) ? w0 : (g == 1) ? w1 : nullptr;
    int e0 = blk * EPB;
    int n = min(EPB, EE - e0);
    for (int i = threadIdx.x; i < CB; i += 256) cnt_s[i] = 0;
    __syncthreads();
    for (int i = threadIdx.x; i < n; i += 256)
        atomicAdd(&cnt_s[D[e0 + i] >> 6], 1);
    __syncthreads();
    if (threadIdx.x == 0) {
        int run = 0;
        for (int i = 0; i < CB; ++i) { off_s[i] = run; run += cnt_s[i]; }
    }
    __syncthreads();
    for (int i = threadIdx.x; i < CB; i += 256) pos_s[i] = off_s[i];
    __syncthreads();
    for (int i = threadIdx.x; i < n; i += 256) {
        int e = e0 + i;
        int d = D[e];
        int p = atomicAdd(&pos_s[d >> 6], 1);
        ushort ewh = (g < 2) ? __half_as_ushort(__float2half(W[e])) : 0;
        lword[p] = ((uint)ewh << 16) | (uint)(S[e] & 0xFFFF);
        ldst[p] = (ushort)d;
    }
    __syncthreads();
    for (int i = threadIdx.x; i < CB; i += 256)
        gbase[i] = atomicAdd(&ccur[g * CB + i], cnt_s[i]);
    __syncthreads();
    const int* rp = rowptr + g * (NN + 1);
    for (int j = threadIdx.x; j < n; j += 256) {
        ushort d = ldst[j];
        int cb = d >> 6;
        int gpos = rp[cb << 6] + gbase[cb] + (j - off_s[cb]);
        ce[(size_t)g * EE + gpos] = lword[j];
        cd[(size_t)g * EE + gpos] = d;
    }
}

// ---------------- pull via LDS accumulation, one block per (g, 64-node window) ----------------
// Wave-per-edge: 64-lane bf16 gather (one 128B line) -> ds_add_f32 into acc[dl][lane].
__global__ __launch_bounds__(256) void pull_lds_cast(const ushort* __restrict__ xh,
                                                     const int* __restrict__ rowptr,
                                                     const uint* __restrict__ ce,
                                                     const ushort* __restrict__ cd,
                                                     const float* __restrict__ invd,
                                                     ushort* __restrict__ aggh) {
    __shared__ float acc[64 * 64];
    int g = blockIdx.x / CB, cb = blockIdx.x % CB;
    int n0 = cb << 6;
    int nw = min(64, NN - n0);
    const int* rp = rowptr + g * (NN + 1);
    int beg = rp[n0], end = rp[n0 + nw];
    for (int i = threadIdx.x; i < 64 * 16; i += 256) ((float4*)acc)[i] = float4{0.f, 0.f, 0.f, 0.f};
    __syncthreads();
    int lane = threadIdx.x & 63, wv = threadIdx.x >> 6;
    for (int i = beg + wv; i < end; i += 4) {
        uint w = ce[(size_t)g * EE + i];
        int dl = (int)cd[(size_t)g * EE + i] - n0;
        int s = (int)(w & 0xFFFF);
        float ww = (g < 2) ? ew_of(w) : 1.0f;
        float v = bf2f(xh[(size_t)s * DD + lane]);
        unsafeAtomicAdd(&acc[dl * 64 + lane], v * ww);
    }
    __syncthreads();
    for (int j = wv; j < nw; j += 4) {
        float sc = invd[g * NN + n0 + j];
        aggh[((size_t)g * NP + n0 + j) * 64 + lane] = f2bf(acc[j * 64 + lane] * sc);
    }
}

__global__ __launch_bounds__(256) void pull_lds_combine(const ushort* __restrict__ xnh, // [3][NP][64]
                                                        const int* __restrict__ rowptr,
                                                        const uint* __restrict__ ce,
                                                        const ushort* __restrict__ cd,
                                                        const float* __restrict__ invd,
                                                        const float* __restrict__ b_pr,
                                                        const float* __restrict__ b_cc,
                                                        const float* __restrict__ b_ap,
                                                        float* __restrict__ o_pr,
                                                        float* __restrict__ o_cc,
                                                        float* __restrict__ o_ap) {
    __shared__ float acc[64 * 64];
    int g = blockIdx.x / CB, cb = blockIdx.x % CB;
    int n0 = cb << 6;
    int nw = min(64, NN - n0);
    const int* rp = rowptr + g * (NN + 1);
    const ushort* x = xnh + (size_t)g * NP * 64;
    int beg = rp[n0], end = rp[n0 + nw];
    for (int i = threadIdx.x; i < 64 * 16; i += 256) ((float4*)acc)[i] = float4{0.f, 0.f, 0.f, 0.f};
    __syncthreads();
    int lane = threadIdx.x & 63, wv = threadIdx.x >> 6;
    for (int i = beg + wv; i < end; i += 4) {
        uint w = ce[(size_t)g * EE + i];
        int dl = (int)cd[(size_t)g * EE + i] - n0;
        int s = (int)(w & 0xFFFF);
        float ww = (g < 2) ? ew_of(w) : 1.0f;
        float v = bf2f(x[(size_t)s * DD + lane]);
        unsafeAtomicAdd(&acc[dl * 64 + lane], v * ww);
    }
    __syncthreads();
    const float* bias = (g == 0) ? b_pr : (g == 1) ? b_cc : b_ap;
    float* out = (g == 0) ? o_pr : (g == 1) ? o_cc : o_ap;
    float bv = bias[lane];
    for (int j = wv; j < nw; j += 4) {
        float sc = invd[g * NN + n0 + j];
        size_t o = (size_t)(n0 + j) * DD + lane;
        out[o] += acc[j * 64 + lane] * sc + bv;
    }
}

// ---------------- consolidated prologue pack (+ zeroing) ----------------
__global__ __launch_bounds__(256) void pack_all(
    const float* __restrict__ pr_Ws0, const float* __restrict__ pr_Wn0,
    const float* __restrict__ cc_Ws0, const float* __restrict__ cc_Wn0,
    const float* __restrict__ pr_Ws1, const float* __restrict__ pr_Wn1,
    const float* __restrict__ cc_Ws1, const float* __restrict__ cc_Wn1,
    const float* __restrict__ ap_Ws0, const float* __restrict__ ap_Wn0,
    const float* __restrict__ ap_Ws1, const float* __restrict__ ap_Wn1,
    const float* __restrict__ k_emb,
    ushort* __restrict__ W0h_pr, ushort* __restrict__ W0h_cc,
    ushort* __restrict__ W1h_pr, ushort* __restrict__ W1h_cc,
    ushort* __restrict__ W0h_ap, ushort* __restrict__ W1h_ap,
    ushort* __restrict__ xh,
    int* __restrict__ zero_base) {
    int b = blockIdx.x;
    int tid = threadIdx.x;
    if (b < 512) {
        int t = (b & 255) * 256 + tid;
        const float* Ws = (b < 256) ? pr_Ws0 : cc_Ws0;
        const float* Wn = (b < 256) ? pr_Wn0 : cc_Wn0;
        ushort* o = (b < 256) ? W0h_pr : W0h_cc;
        int c = t >> 7, k = t & 127;
        o[t] = f2bf((k < 64) ? Ws[k * 512 + c] : Wn[(k - 64) * 512 + c]);
    } else if (b < 1024) {
        int t = ((b - 512) & 255) * 256 + tid;
        const float* Ws = (b < 768) ? pr_Ws1 : cc_Ws1;
        const float* Wn = (b < 768) ? pr_Wn1 : cc_Wn1;
        ushort* o = (b < 768) ? W1h_pr : W1h_cc;
        int c = t >> 9, k = t & 511;
        o[t] = f2bf((c < 64) ? Ws[k * 64 + c] : Wn[k * 64 + (c - 64)]);
    } else if (b < 1056) {
        int t = (b - 1024) * 256 + tid;
        int c = t >> 7, k = t & 127;
        W0h_ap[t] = f2bf((k < 64) ? ap_Ws0[k * 64 + c] : ap_Wn0[(k - 64) * 64 + c]);
    } else if (b < 1088) {
        int t = (b - 1056) * 256 + tid;
        int c = t >> 6, k = t & 63;
        W1h_ap[t] = f2bf((c < 64) ? ap_Ws1[k * 64 + c] : ap_Wn1[k * 64 + (c - 64)]);
    } else if (b < 1088 + ZERO_BLOCKS) {
        int t = (b - 1088) * 256 + tid;
        if (t < ZERO_N) zero_base[t] = 0;
    } else {
        int t = (b - 1088 - ZERO_BLOCKS) * 256 + tid;
        if (t < NN * DD) xh[t] = f2bf(k_emb[t]);
    }
}

// ---------------- FUSED layer0+layer1 v4 (bf16 xn out) ----------------
__global__ __launch_bounds__(512, 4) void fused_sage4(
    const ushort* __restrict__ xh,    // [NP][64]
    const ushort* __restrict__ aggA,  // [branches][NP][64]
    const ushort* __restrict__ W0a, const ushort* __restrict__ W1a,
    const ushort* __restrict__ W0b, const ushort* __restrict__ W1b,
    const float* __restrict__ b0a, const float* __restrict__ b0b,
    float* __restrict__ outS0, float* __restrict__ outS1,
    ushort* __restrict__ xnh, int nblk) {
    constexpr int LROW = 136;
    __shared__ ushort Ahs[64 * LROW];
    __shared__ ushort h1s[64 * LROW];
    int br = blockIdx.x / nblk;
    int rb = blockIdx.x % nblk;
    const ushort* W0 = br ? W0b : W0a;
    const ushort* W1 = br ? W1b : W1a;
    const float* b0 = br ? b0b : b0a;
    float* outS = br ? outS1 : outS0;
    ushort* outX = xnh + (size_t)br * NP * 64;
    const ushort* agg = aggA + (size_t)br * NP * 64;
    int row0 = rb * 64;

    int wv = threadIdx.x >> 6;
    int lane = threadIdx.x & 63;
    int lrow = lane & 15;
    int koff = (lane >> 4) * 8;
    int crow = (lane >> 4) * 4;

    {
        int r = threadIdx.x >> 3;
        int seg = threadIdx.x & 7;
        const ushort* src = (seg < 4) ? (xh + (size_t)(row0 + r) * 64 + seg * 16)
                                      : (agg + (size_t)(row0 + r) * 64 + (seg - 4) * 16);
        *(short8*)&Ahs[r * LROW + seg * 16] = *(const short8*)src;
        *(short8*)&Ahs[r * LROW + seg * 16 + 8] = *(const short8*)(src + 8);
    }
    __syncthreads();

    f32x4 C[4] = {};
#pragma unroll
    for (int p = 0; p < 4; ++p) {
        {
            short8 B[4];
#pragma unroll
            for (int kk = 0; kk < 4; ++kk)
                B[kk] = *(const short8*)(W0 + (size_t)(p * 128 + wv * 16 + lrow) * 128 + kk * 32 + koff);
            f32x4 acc[4] = {};
#pragma unroll
            for (int rg = 0; rg < 4; ++rg) {
#pragma unroll
                for (int kk = 0; kk < 4; ++kk) {
                    short8 a = *(const short8*)&Ahs[(rg * 16 + lrow) * LROW + kk * 32 + koff];
                    acc[rg] = __builtin_amdgcn_mfma_f32_16x16x32_bf16(a, B[kk], acc[rg], 0, 0, 0);
                }
            }
            float bb = b0[p * 128 + wv * 16 + lrow];
#pragma unroll
            for (int rg = 0; rg < 4; ++rg) {
#pragma unroll
                for (int r = 0; r < 4; ++r) {
                    float v = fmaxf(acc[rg][r] + bb, 0.0f);
                    h1s[(rg * 16 + crow + r) * LROW + wv * 16 + lrow] = f2bf(v);
                }
            }
        }
        __syncthreads();
        {
            short8 B[4];
#pragma unroll
            for (int kc = 0; kc < 4; ++kc)
                B[kc] = *(const short8*)(W1 + (size_t)(wv * 16 + lrow) * HH + p * 128 + kc * 32 + koff);
#pragma unroll
            for (int rg = 0; rg < 4; ++rg) {
#pragma unroll
                for (int kc = 0; kc < 4; ++kc) {
                    short8 a = *(const short8*)&h1s[(rg * 16 + lrow) * LROW + kc * 32 + koff];
                    C[rg] = __builtin_amdgcn_mfma_f32_16x16x32_bf16(a, B[kc], C[rg], 0, 0, 0);
                }
            }
        }
        __syncthreads();
    }
    int col = wv * 16 + lrow;
    if (col < 64) {
        float* o = outS + col;
#pragma unroll
        for (int rg = 0; rg < 4; ++rg)
#pragma unroll
            for (int r = 0; r < 4; ++r) {
                int row = row0 + rg * 16 + crow + r;
                if (row < NN) o[(size_t)row * 64] = C[rg][r];
            }
    } else {
        ushort* o = outX + (col - 64);
#pragma unroll
        for (int rg = 0; rg < 4; ++rg)
#pragma unroll
            for (int r = 0; r < 4; ++r) {
                int row = row0 + rg * 16 + crow + r;
                if (row < NN) o[(size_t)row * 64] = f2bf(C[rg][r]);
            }
    }
}

// ---------------- FUSED ap branch (bf16 xn out) ----------------
__global__ __launch_bounds__(256, 4) void fused_sage_ap(
    const ushort* __restrict__ xh,
    const ushort* __restrict__ agg,
    const ushort* __restrict__ W0,
    const ushort* __restrict__ W1,
    const float* __restrict__ b0,
    float* __restrict__ outS,
    ushort* __restrict__ outX) {
    constexpr int LROW = 72;
    __shared__ ushort h1s[16 * LROW];
    int wv = threadIdx.x >> 6;
    int lane = threadIdx.x & 63;
    int lrow = lane & 15;
    int koff = (lane >> 4) * 8;
    int crow = (lane >> 4) * 4;
    int row0 = blockIdx.x * 16;

    {
        const size_t aoff = (size_t)(row0 + lrow) * 64 + koff;
        short8 aF[4];
#pragma unroll
        for (int kk = 0; kk < 2; ++kk) {
            aF[kk]     = *(const short8*)(xh + aoff + kk * 32);
            aF[2 + kk] = *(const short8*)(agg + aoff + kk * 32);
        }
        f32x4 acc = {};
#pragma unroll
        for (int kk = 0; kk < 4; ++kk) {
            short8 b = *(const short8*)(W0 + (size_t)(wv * 16 + lrow) * 128 + kk * 32 + koff);
            acc = __builtin_amdgcn_mfma_f32_16x16x32_bf16(aF[kk], b, acc, 0, 0, 0);
        }
        float bb = b0[wv * 16 + lrow];
#pragma unroll
        for (int r = 0; r < 4; ++r) {
            h1s[(crow + r) * LROW + wv * 16 + lrow] = f2bf(fmaxf(acc[r] + bb, 0.0f));
        }
    }
    __syncthreads();
    {
        f32x4 C2[2] = {};
#pragma unroll
        for (int kc = 0; kc < 2; ++kc) {
            short8 a = *(const short8*)&h1s[lrow * LROW + kc * 32 + koff];
#pragma unroll
            for (int c = 0; c < 2; ++c) {
                short8 b = *(const short8*)(W1 + (size_t)(wv * 32 + c * 16 + lrow) * 64 + kc * 32 + koff);
                C2[c] = __builtin_amdgcn_mfma_f32_16x16x32_bf16(a, b, C2[c], 0, 0, 0);
            }
        }
#pragma unroll
        for (int c = 0; c < 2; ++c) {
            int col = wv * 32 + c * 16 + lrow;
#pragma unroll
            for (int r = 0; r < 4; ++r) {
                int row = row0 + crow + r;
                if (row < NN) {
                    if (col < 64) outS[(size_t)row * 64 + col] = C2[c][r];
                    else outX[(size_t)row * 64 + (col - 64)] = f2bf(C2[c][r]);
                }
            }
        }
    }
}

// ---------------- attention reduction ----------------
__global__ __launch_bounds__(256) void att_stage1(const float* __restrict__ pr,
                                                  const float* __restrict__ cc,
                                                  const float* __restrict__ ap,
                                                  const float* __restrict__ attW,
                                                  const float* __restrict__ attb,
                                                  float2* __restrict__ partial) {
    __shared__ float red[8];
    int lane = threadIdx.x & 63;
    int wv = threadIdx.x >> 6;
    int gw = blockIdx.x * 4 + wv;
    const int nwaves = ATT_BLOCKS * 4;
    float b = attb[lane];
    float c0 = 0.f, c1 = 0.f;
    for (int n = gw; n < NN; n += nwaves) {
        float p0 = 0.f, p1 = 0.f;
        for (int k = 0; k < DD; ++k) {
            float w = attW[k * DD + lane];
            p0 = fmaf(pr[n * DD + k], w, p0);
            p1 = fmaf(cc[n * DD + k], w, p1);
        }
        float a = ap[n * DD + lane];
        c0 += a * tanhf(p0 + b);
        c1 += a * tanhf(p1 + b);
    }
#pragma unroll
    for (int off = 32; off; off >>= 1) {
        c0 += __shfl_xor(c0, off);
        c1 += __shfl_xor(c1, off);
    }
    if (lane == 0) { red[wv * 2] = c0; red[wv * 2 + 1] = c1; }
    __syncthreads();
    if (threadIdx.x == 0) {
        partial[blockIdx.x] = make_float2(red[0] + red[2] + red[4] + red[6],
                                          red[1] + red[3] + red[5] + red[7]);
    }
}

__global__ __launch_bounds__(64) void att_stage2(const float2* __restrict__ partial,
                                                 float* __restrict__ w_acc) {
    int lane = threadIdx.x;
    float s0 = 0.f, s1 = 0.f;
    for (int i = lane; i < ATT_BLOCKS; i += 64) {
        float2 p = partial[i];
        s0 += p.x; s1 += p.y;
    }
#pragma unroll
    for (int off = 32; off; off >>= 1) {
        s0 += __shfl_xor(s0, off);
        s1 += __shfl_xor(s1, off);
    }
    if (lane == 0) { w_acc[0] = s0; w_acc[1] = s1; }
}

// ---------------- final (in-place on pr=out) ----------------
__global__ __launch_bounds__(256) void final_kernel(float* __restrict__ pr_out,
                                                    const float* __restrict__ cc,
                                                    const float* __restrict__ w_acc) {
    int t = blockIdx.x * blockDim.x + threadIdx.x;
    if (t >= NN * DD) return;
    float w0 = w_acc[0] * (1.0f / NN);
    float w1 = w_acc[1] * (1.0f / NN);
    float m = fmaxf(w0, w1);
    float e0 = __expf(w0 - m), e1 = __expf(w1 - m);
    float inv = 1.0f / (e0 + e1);
    pr_out[t] = (e0 * pr_out[t] + e1 * cc[t]) * inv;
}

extern "C" void kernel_launch(void* const* d_in, const int* in_sizes, int n_in,
                              void* d_out, int out_size, void* d_ws, size_t ws_size,
                              hipStream_t stream) {
    const float* k_emb  = (const float*)d_in[0];
    const int*   pr_src = (const int*)d_in[1];
    const int*   pr_dst = (const int*)d_in[2];
    const float* pr_ew  = (const float*)d_in[3];
    const int*   cc_src = (const int*)d_in[4];
    const int*   cc_dst = (const int*)d_in[5];
    const float* cc_ew  = (const float*)d_in[6];
    const int*   sps_src = (const int*)d_in[7];
    const int*   sps_dst = (const int*)d_in[8];
    const float* pr_Ws0 = (const float*)d_in[9];
    const float* pr_Wn0 = (const float*)d_in[10];
    const float* pr_b0  = (const float*)d_in[11];
    const float* pr_Ws1 = (const float*)d_in[12];
    const float* pr_Wn1 = (const float*)d_in[13];
    const float* pr_b1  = (const float*)d_in[14];
    const float* cc_Ws0 = (const float*)d_in[15];
    const float* cc_Wn0 = (const float*)d_in[16];
    const float* cc_b0  = (const float*)d_in[17];
    const float* cc_Ws1 = (const float*)d_in[18];
    const float* cc_Wn1 = (const float*)d_in[19];
    const float* cc_b1  = (const float*)d_in[20];
    const float* ap_Ws0 = (const float*)d_in[21];
    const float* ap_Wn0 = (const float*)d_in[22];
    const float* ap_b0  = (const float*)d_in[23];
    const float* ap_Ws1 = (const float*)d_in[24];
    const float* ap_Wn1 = (const float*)d_in[25];
    const float* ap_b1  = (const float*)d_in[26];
    const float* att_W  = (const float*)d_in[27];
    const float* att_b  = (const float*)d_in[28];
    float* out = (float*)d_out;

    // ---- workspace layout (256B-aligned) ----
    char* base = (char*)d_ws;
    size_t off = 0;
    auto alloc = [&](size_t bytes) -> void* {
        void* p = base + off;
        off = (off + bytes + 255) & ~(size_t)255;
        return p;
    };
    float*  invd   = (float*)alloc((size_t)3 * NN * 4);
    int*    cnt    = (int*)alloc((size_t)ZERO_N * 4);  // cnt + ccur, zeroed in pack_all
    int*    ccur   = cnt + 3 * NN;
    int*    rowptr = (int*)alloc((size_t)3 * (NN + 1) * 4);
    uint*   ce     = (uint*)alloc((size_t)3 * EE * 4);
    ushort* cd     = (ushort*)alloc((size_t)3 * EE * 2);
    float*  w_acc  = (float*)alloc(64);
    float2* att_partial = (float2*)alloc(ATT_BLOCKS * 8);
    ushort* xnh    = (ushort*)alloc((size_t)3 * NP * DD * 2);
    float*  out_cc = (float*)alloc((size_t)NN * DD * 4);
    float*  out_ap = (float*)alloc((size_t)NN * DD * 4);
    ushort* xh     = (ushort*)alloc((size_t)NP * DD * 2);
    ushort* aggh   = (ushort*)alloc((size_t)3 * NP * DD * 2);
    ushort* W0h_pr = (ushort*)alloc(512 * 128 * 2);
    ushort* W0h_cc = (ushort*)alloc(512 * 128 * 2);
    ushort* W0h_ap = (ushort*)alloc(64 * 128 * 2);
    ushort* W1h_pr = (ushort*)alloc(128 * 512 * 2);
    ushort* W1h_cc = (ushort*)alloc(128 * 512 * 2);
    ushort* W1h_ap = (ushort*)alloc(128 * 64 * 2);
    float*  out_pr = out;

    const int TB = 256;
    const int blocks_ND = (NN * DD) / TB;   // 5000
    const int NBLK64 = NP / 64;             // 313

    // ---- prologue ----
    pack_all<<<1088 + ZERO_BLOCKS + blocks_ND, TB, 0, stream>>>(
        pr_Ws0, pr_Wn0, cc_Ws0, cc_Wn0, pr_Ws1, pr_Wn1, cc_Ws1, cc_Wn1,
        ap_Ws0, ap_Wn0, ap_Ws1, ap_Wn1, k_emb,
        W0h_pr, W0h_cc, W1h_pr, W1h_cc, W0h_ap, W1h_ap, xh, cnt);

    hist3<<<3 * BLOCKS_E, TB, 0, stream>>>(pr_dst, cc_dst, sps_dst, cnt);
    scan_kernel<<<3, 1024, 0, stream>>>(cnt, rowptr, invd);
    bucket_coarse<<<3 * B1_BLOCKS, TB, 0, stream>>>(pr_src, pr_dst, pr_ew,
                                                    cc_src, cc_dst, cc_ew,
                                                    sps_src, sps_dst,
                                                    rowptr, ccur, ce, cd);

    // ---- layer-0 aggregation: LDS-accumulated pull over coarse stream ----
    pull_lds_cast<<<3 * CB, TB, 0, stream>>>(xh, rowptr, ce, cd, invd, aggh);

    // ---- fused layer0+layer1 ----
    fused_sage4<<<2 * NBLK64, 512, 0, stream>>>(
        xh, aggh,
        W0h_pr, W1h_pr, W0h_cc, W1h_cc,
        pr_b0, cc_b0, out_pr, out_cc, xnh, NBLK64);
    fused_sage_ap<<<NP / 16, 256, 0, stream>>>(
        xh, aggh + (size_t)2 * NP * 64,
        W0h_ap, W1h_ap, ap_b0, out_ap, xnh + (size_t)2 * NP * 64);

    // ---- layer-1 aggregation + combine: LDS-accumulated pull ----
    pull_lds_combine<<<3 * CB, TB, 0, stream>>>(xnh, rowptr, ce, cd, invd,
                                                pr_b1, cc_b1, ap_b1,
                                                out_pr, out_cc, out_ap);

    // ---- attention fusion ----
    att_stage1<<<ATT_BLOCKS, TB, 0, stream>>>(out_pr, out_cc, out_ap, att_W, att_b, att_partial);
    att_stage2<<<1, 64, 0, stream>>>(att_partial, w_acc);
    final_kernel<<<blocks_ND, TB, 0, stream>>>(out_pr, out_cc, w_acc);
}

// Round 17
// 272.542 us; speedup vs baseline: 3.3080x; 3.3080x over previous
//
#include <hip/hip_runtime.h>
#include <hip/hip_fp16.h>

#define NN 20000   // nodes
#define NP 20032   // padded nodes (313*64)
#define DD 64      // emb dim
#define HH 512     // hidden
#define EE 320000  // edges per graph
#define ATT_BLOCKS 625
#define CB 157              // coarse buckets (dst>>7)
#define EPB 4096            // edges per bucket_coarse block
#define B1_BLOCKS ((EE + EPB - 1) / EPB)  // 79
#define ZERO_N (3 * NN + 3 * CB)
#define ZERO_BLOCKS ((ZERO_N + 255) / 256)

typedef __attribute__((ext_vector_type(8))) short short8;
typedef __attribute__((ext_vector_type(4))) float f32x4;

__device__ __forceinline__ ushort f2bf(float f) {
    union { float f; unsigned u; } v; v.f = f;
    unsigned r = v.u + 0x7FFF + ((v.u >> 16) & 1);   // RNE
    return (ushort)(r >> 16);
}
__device__ __forceinline__ float bf2f(ushort h) {
    union { unsigned u; float f; } v; v.u = ((unsigned)h) << 16;
    return v.f;
}
__device__ __forceinline__ float ew_of(uint w) {
    __half h = __ushort_as_half((ushort)(w >> 16));
    return __half2float(h);
}

// ---------------- CSR histogram (4 edges/thread) ----------------
__global__ __launch_bounds__(256) void hist3(const int* __restrict__ d0,
                                             const int* __restrict__ d1,
                                             const int* __restrict__ d2,
                                             int* __restrict__ cnt) {
    const int BE = (EE + 1023) / 1024;   // blocks per graph = 313
    int g = blockIdx.x / BE;
    int base = (blockIdx.x % BE) * 1024 + threadIdx.x * 4;
    const int* d = (g == 0) ? d0 : (g == 1) ? d1 : d2;
    int* c = cnt + g * NN;
#pragma unroll
    for (int j = 0; j < 4; ++j) {
        int e = base + j;
        if (e < EE) atomicAdd(&c[d[e]], 1);
    }
}

// scan + invd fused: one block per graph
__global__ __launch_bounds__(1024) void scan_kernel(const int* __restrict__ cnt,
                                                    int* __restrict__ rowptr,
                                                    float* __restrict__ invd) {
    __shared__ int part[1024];
    int g = blockIdx.x;
    const int* c = cnt + g * NN;
    int* rp = rowptr + g * (NN + 1);
    int tid = threadIdx.x;
    const int CH = (NN + 1023) / 1024;
    int i0 = tid * CH;
    int s = 0;
    for (int i = 0; i < CH; ++i) { int idx = i0 + i; if (idx < NN) s += c[idx]; }
    part[tid] = s;
    __syncthreads();
    for (int off = 1; off < 1024; off <<= 1) {
        int v = (tid >= off) ? part[tid - off] : 0;
        __syncthreads();
        part[tid] += v;
        __syncthreads();
    }
    int run = (tid > 0) ? part[tid - 1] : 0;
    for (int i = 0; i < CH; ++i) {
        int idx = i0 + i;
        if (idx < NN) {
            int cv = c[idx];
            rp[idx] = run; run += cv;
            invd[g * NN + idx] = 1.0f / fmaxf((float)cv, 1.0f);
        }
    }
    if (tid == 1023) rp[NN] = part[1023];
}

// ---------------- bucket pass 1: coarse partition, 4B packed edge ----------------
__global__ __launch_bounds__(256) void bucket_coarse(
    const int* __restrict__ s0, const int* __restrict__ d0, const float* __restrict__ w0,
    const int* __restrict__ s1, const int* __restrict__ d1, const float* __restrict__ w1,
    const int* __restrict__ s2, const int* __restrict__ d2,
    const int* __restrict__ rowptr,
    int* __restrict__ ccur,          // [3*CB], zeroed by pack_all
    uint* __restrict__ ce,           // [3*EE] coarse packed {ew_f16<<16 | src}
    ushort* __restrict__ cd) {       // [3*EE] coarse dst
    __shared__ int cnt_s[CB];
    __shared__ int off_s[CB];
    __shared__ int pos_s[CB];
    __shared__ int gbase[CB];
    __shared__ uint lword[EPB];
    __shared__ ushort ldst[EPB];
    int g = blockIdx.x / B1_BLOCKS;
    int blk = blockIdx.x % B1_BLOCKS;
    const int* S = (g == 0) ? s0 : (g == 1) ? s1 : s2;
    const int* D = (g == 0) ? d0 : (g == 1) ? d1 : d2;
    const float* W = (g == 0) ? w0 : (g == 1) ? w1 : nullptr;
    int e0 = blk * EPB;
    int n = min(EPB, EE - e0);
    for (int i = threadIdx.x; i < CB; i += 256) cnt_s[i] = 0;
    __syncthreads();
    for (int i = threadIdx.x; i < n; i += 256)
        atomicAdd(&cnt_s[D[e0 + i] >> 7], 1);
    __syncthreads();
    if (threadIdx.x == 0) {
        int run = 0;
        for (int i = 0; i < CB; ++i) { off_s[i] = run; run += cnt_s[i]; }
    }
    __syncthreads();
    if (threadIdx.x < CB) pos_s[threadIdx.x] = off_s[threadIdx.x];
    __syncthreads();
    for (int i = threadIdx.x; i < n; i += 256) {
        int e = e0 + i;
        int d = D[e];
        int p = atomicAdd(&pos_s[d >> 7], 1);
        ushort ewh = (g < 2) ? __half_as_ushort(__float2half(W[e])) : 0;
        lword[p] = ((uint)ewh << 16) | (uint)(S[e] & 0xFFFF);
        ldst[p] = (ushort)d;
    }
    __syncthreads();
    if (threadIdx.x < CB)
        gbase[threadIdx.x] = atomicAdd(&ccur[g * CB + threadIdx.x], cnt_s[threadIdx.x]);
    __syncthreads();
    const int* rp = rowptr + g * (NN + 1);
    for (int j = threadIdx.x; j < n; j += 256) {
        ushort d = ldst[j];
        int cb = d >> 7;
        int gpos = rp[cb << 7] + gbase[cb] + (j - off_s[cb]);
        ce[(size_t)g * EE + gpos] = lword[j];
        cd[(size_t)g * EE + gpos] = d;
    }
}

// ---------------- bucket pass 2: fine scatter within coarse window ----------------
__global__ __launch_bounds__(256) void bucket_fine(
    const int* __restrict__ rowptr,
    const uint* __restrict__ ce, const ushort* __restrict__ cd,
    uint* __restrict__ edge_s,      // [2*EE] final pr/cc packed
    ushort* __restrict__ src_s2) {  // [EE] final sps src
    __shared__ int rp_s[129];
    __shared__ int cur_s[128];
    int g = blockIdx.x / CB;
    int cb = blockIdx.x % CB;
    const int* rp = rowptr + g * (NN + 1);
    int n0 = cb << 7;
    int n1 = min(n0 + 128, NN);
    int m = n1 - n0;
    if (threadIdx.x <= m) rp_s[threadIdx.x] = rp[n0 + threadIdx.x];
    if (threadIdx.x < m) cur_s[threadIdx.x] = 0;
    __syncthreads();
    int beg = rp_s[0], end = rp_s[m];
    for (int j = beg + threadIdx.x; j < end; j += 256) {
        uint e = ce[(size_t)g * EE + j];
        int dl = (int)cd[(size_t)g * EE + j] - n0;
        int pos = rp_s[dl] + atomicAdd(&cur_s[dl], 1);
        if (g < 2) edge_s[(size_t)g * EE + pos] = e;
        else src_s2[pos] = (ushort)(e & 0xFFFF);
    }
}

// ---------------- pull aggregation: quarter-wave gather (4 edges/trip, 8B/lane) ----------------
__global__ __launch_bounds__(256) void pull_cast3(const ushort* __restrict__ xh,  // [NP][64] bf16
                                                  const int* __restrict__ rowptr,
                                                  const uint* __restrict__ edge_s,
                                                  const ushort* __restrict__ src_s2,
                                                  const float* __restrict__ invd,
                                                  ushort* __restrict__ aggh) {
    int wid = (blockIdx.x * 256 + threadIdx.x) >> 6;
    int lane = threadIdx.x & 63;
    if (wid >= 3 * NN) return;
    int g = wid / NN, n = wid % NN;
    const int* rp = rowptr + g * (NN + 1);
    int beg = rp[n], end = rp[n + 1];
    int q = lane >> 4, fl = lane & 15;
    float a0 = 0.f, a1 = 0.f, a2 = 0.f, a3 = 0.f;
    for (int i = beg; i < end; i += 4) {
        int e = i + q;
        bool valid = e < end;
        int s; float w;
        if (g < 2) {
            uint ew = valid ? edge_s[(size_t)g * EE + e] : 0u;
            s = (int)(ew & 0xFFFF);
            w = valid ? ew_of(ew) : 0.f;
        } else {
            s = valid ? (int)src_s2[e] : 0;
            w = valid ? 1.f : 0.f;
        }
        ushort4 v = *(const ushort4*)(xh + (size_t)s * DD + fl * 4);
        a0 = fmaf(bf2f(v.x), w, a0);
        a1 = fmaf(bf2f(v.y), w, a1);
        a2 = fmaf(bf2f(v.z), w, a2);
        a3 = fmaf(bf2f(v.w), w, a3);
    }
    a0 += __shfl_xor(a0, 16); a0 += __shfl_xor(a0, 32);
    a1 += __shfl_xor(a1, 16); a1 += __shfl_xor(a1, 32);
    a2 += __shfl_xor(a2, 16); a2 += __shfl_xor(a2, 32);
    a3 += __shfl_xor(a3, 16); a3 += __shfl_xor(a3, 32);
    if (q == 0) {
        float sc = invd[g * NN + n];
        ushort4 o;
        o.x = f2bf(a0 * sc); o.y = f2bf(a1 * sc); o.z = f2bf(a2 * sc); o.w = f2bf(a3 * sc);
        *(ushort4*)(aggh + ((size_t)g * NP + n) * 64 + fl * 4) = o;
    }
}

__global__ __launch_bounds__(256) void pull_combine3(const ushort* __restrict__ xnh, // [3][NP][64] bf16
                                                     const int* __restrict__ rowptr,
                                                     const uint* __restrict__ edge_s,
                                                     const ushort* __restrict__ src_s2,
                                                     const float* __restrict__ invd,
                                                     const float* __restrict__ b_pr,
                                                     const float* __restrict__ b_cc,
                                                     const float* __restrict__ b_ap,
                                                     float* __restrict__ o_pr,
                                                     float* __restrict__ o_cc,
                                                     float* __restrict__ o_ap) {
    int wid = (blockIdx.x * 256 + threadIdx.x) >> 6;
    int lane = threadIdx.x & 63;
    if (wid >= 3 * NN) return;
    int g = wid / NN, n = wid % NN;
    const int* rp = rowptr + g * (NN + 1);
    const ushort* x = xnh + (size_t)g * NP * 64;
    int beg = rp[n], end = rp[n + 1];
    int q = lane >> 4, fl = lane & 15;
    float a0 = 0.f, a1 = 0.f, a2 = 0.f, a3 = 0.f;
    for (int i = beg; i < end; i += 4) {
        int e = i + q;
        bool valid = e < end;
        int s; float w;
        if (g < 2) {
            uint ew = valid ? edge_s[(size_t)g * EE + e] : 0u;
            s = (int)(ew & 0xFFFF);
            w = valid ? ew_of(ew) : 0.f;
        } else {
            s = valid ? (int)src_s2[e] : 0;
            w = valid ? 1.f : 0.f;
        }
        ushort4 v = *(const ushort4*)(x + (size_t)s * DD + fl * 4);
        a0 = fmaf(bf2f(v.x), w, a0);
        a1 = fmaf(bf2f(v.y), w, a1);
        a2 = fmaf(bf2f(v.z), w, a2);
        a3 = fmaf(bf2f(v.w), w, a3);
    }
    a0 += __shfl_xor(a0, 16); a0 += __shfl_xor(a0, 32);
    a1 += __shfl_xor(a1, 16); a1 += __shfl_xor(a1, 32);
    a2 += __shfl_xor(a2, 16); a2 += __shfl_xor(a2, 32);
    a3 += __shfl_xor(a3, 16); a3 += __shfl_xor(a3, 32);
    if (q == 0) {
        float sc = invd[g * NN + n];
        const float* bias = (g == 0) ? b_pr : (g == 1) ? b_cc : b_ap;
        float* out = (g == 0) ? o_pr : (g == 1) ? o_cc : o_ap;
        float4 ov = *(float4*)(out + (size_t)n * DD + fl * 4);
        float4 bv = *(const float4*)(bias + fl * 4);
        ov.x += a0 * sc + bv.x;
        ov.y += a1 * sc + bv.y;
        ov.z += a2 * sc + bv.z;
        ov.w += a3 * sc + bv.w;
        *(float4*)(out + (size_t)n * DD + fl * 4) = ov;
    }
}

// ---------------- consolidated prologue pack (+ zeroing) ----------------
__global__ __launch_bounds__(256) void pack_all(
    const float* __restrict__ pr_Ws0, const float* __restrict__ pr_Wn0,
    const float* __restrict__ cc_Ws0, const float* __restrict__ cc_Wn0,
    const float* __restrict__ pr_Ws1, const float* __restrict__ pr_Wn1,
    const float* __restrict__ cc_Ws1, const float* __restrict__ cc_Wn1,
    const float* __restrict__ ap_Ws0, const float* __restrict__ ap_Wn0,
    const float* __restrict__ ap_Ws1, const float* __restrict__ ap_Wn1,
    const float* __restrict__ k_emb,
    ushort* __restrict__ W0h_pr, ushort* __restrict__ W0h_cc,
    ushort* __restrict__ W1h_pr, ushort* __restrict__ W1h_cc,
    ushort* __restrict__ W0h_ap, ushort* __restrict__ W1h_ap,
    ushort* __restrict__ xh,
    int* __restrict__ zero_base) {
    int b = blockIdx.x;
    int tid = threadIdx.x;
    if (b < 512) {
        int t = (b & 255) * 256 + tid;
        const float* Ws = (b < 256) ? pr_Ws0 : cc_Ws0;
        const float* Wn = (b < 256) ? pr_Wn0 : cc_Wn0;
        ushort* o = (b < 256) ? W0h_pr : W0h_cc;
        int c = t >> 7, k = t & 127;
        o[t] = f2bf((k < 64) ? Ws[k * 512 + c] : Wn[(k - 64) * 512 + c]);
    } else if (b < 1024) {
        int t = ((b - 512) & 255) * 256 + tid;
        const float* Ws = (b < 768) ? pr_Ws1 : cc_Ws1;
        const float* Wn = (b < 768) ? pr_Wn1 : cc_Wn1;
        ushort* o = (b < 768) ? W1h_pr : W1h_cc;
        int c = t >> 9, k = t & 511;
        o[t] = f2bf((c < 64) ? Ws[k * 64 + c] : Wn[k * 64 + (c - 64)]);
    } else if (b < 1056) {
        int t = (b - 1024) * 256 + tid;
        int c = t >> 7, k = t & 127;
        W0h_ap[t] = f2bf((k < 64) ? ap_Ws0[k * 64 + c] : ap_Wn0[(k - 64) * 64 + c]);
    } else if (b < 1088) {
        int t = (b - 1056) * 256 + tid;
        int c = t >> 6, k = t & 63;
        W1h_ap[t] = f2bf((c < 64) ? ap_Ws1[k * 64 + c] : ap_Wn1[k * 64 + (c - 64)]);
    } else if (b < 1088 + ZERO_BLOCKS) {
        int t = (b - 1088) * 256 + tid;
        if (t < ZERO_N) zero_base[t] = 0;
    } else {
        int t = (b - 1088 - ZERO_BLOCKS) * 256 + tid;
        if (t < NN * DD) xh[t] = f2bf(k_emb[t]);
    }
}

// ---------------- FUSED layer0+layer1 v4 (bf16 xn out) ----------------
__global__ __launch_bounds__(512, 4) void fused_sage4(
    const ushort* __restrict__ xh,    // [NP][64]
    const ushort* __restrict__ aggA,  // [branches][NP][64]
    const ushort* __restrict__ W0a, const ushort* __restrict__ W1a,
    const ushort* __restrict__ W0b, const ushort* __restrict__ W1b,
    const float* __restrict__ b0a, const float* __restrict__ b0b,
    float* __restrict__ outS0, float* __restrict__ outS1,
    ushort* __restrict__ xnh, int nblk) {
    constexpr int LROW = 136;
    __shared__ ushort Ahs[64 * LROW];
    __shared__ ushort h1s[64 * LROW];
    int br = blockIdx.x / nblk;
    int rb = blockIdx.x % nblk;
    const ushort* W0 = br ? W0b : W0a;
    const ushort* W1 = br ? W1b : W1a;
    const float* b0 = br ? b0b : b0a;
    float* outS = br ? outS1 : outS0;
    ushort* outX = xnh + (size_t)br * NP * 64;
    const ushort* agg = aggA + (size_t)br * NP * 64;
    int row0 = rb * 64;

    int wv = threadIdx.x >> 6;
    int lane = threadIdx.x & 63;
    int lrow = lane & 15;
    int koff = (lane >> 4) * 8;
    int crow = (lane >> 4) * 4;

    {
        int r = threadIdx.x >> 3;
        int seg = threadIdx.x & 7;
        const ushort* src = (seg < 4) ? (xh + (size_t)(row0 + r) * 64 + seg * 16)
                                      : (agg + (size_t)(row0 + r) * 64 + (seg - 4) * 16);
        *(short8*)&Ahs[r * LROW + seg * 16] = *(const short8*)src;
        *(short8*)&Ahs[r * LROW + seg * 16 + 8] = *(const short8*)(src + 8);
    }
    __syncthreads();

    f32x4 C[4] = {};
#pragma unroll
    for (int p = 0; p < 4; ++p) {
        {
            short8 B[4];
#pragma unroll
            for (int kk = 0; kk < 4; ++kk)
                B[kk] = *(const short8*)(W0 + (size_t)(p * 128 + wv * 16 + lrow) * 128 + kk * 32 + koff);
            f32x4 acc[4] = {};
#pragma unroll
            for (int rg = 0; rg < 4; ++rg) {
#pragma unroll
                for (int kk = 0; kk < 4; ++kk) {
                    short8 a = *(const short8*)&Ahs[(rg * 16 + lrow) * LROW + kk * 32 + koff];
                    acc[rg] = __builtin_amdgcn_mfma_f32_16x16x32_bf16(a, B[kk], acc[rg], 0, 0, 0);
                }
            }
            float bb = b0[p * 128 + wv * 16 + lrow];
#pragma unroll
            for (int rg = 0; rg < 4; ++rg) {
#pragma unroll
                for (int r = 0; r < 4; ++r) {
                    float v = fmaxf(acc[rg][r] + bb, 0.0f);
                    h1s[(rg * 16 + crow + r) * LROW + wv * 16 + lrow] = f2bf(v);
                }
            }
        }
        __syncthreads();
        {
            short8 B[4];
#pragma unroll
            for (int kc = 0; kc < 4; ++kc)
                B[kc] = *(const short8*)(W1 + (size_t)(wv * 16 + lrow) * HH + p * 128 + kc * 32 + koff);
#pragma unroll
            for (int rg = 0; rg < 4; ++rg) {
#pragma unroll
                for (int kc = 0; kc < 4; ++kc) {
                    short8 a = *(const short8*)&h1s[(rg * 16 + lrow) * LROW + kc * 32 + koff];
                    C[rg] = __builtin_amdgcn_mfma_f32_16x16x32_bf16(a, B[kc], C[rg], 0, 0, 0);
                }
            }
        }
        __syncthreads();
    }
    int col = wv * 16 + lrow;
    if (col < 64) {
        float* o = outS + col;
#pragma unroll
        for (int rg = 0; rg < 4; ++rg)
#pragma unroll
            for (int r = 0; r < 4; ++r) {
                int row = row0 + rg * 16 + crow + r;
                if (row < NN) o[(size_t)row * 64] = C[rg][r];
            }
    } else {
        ushort* o = outX + (col - 64);
#pragma unroll
        for (int rg = 0; rg < 4; ++rg)
#pragma unroll
            for (int r = 0; r < 4; ++r) {
                int row = row0 + rg * 16 + crow + r;
                if (row < NN) o[(size_t)row * 64] = f2bf(C[rg][r]);
            }
    }
}

// ---------------- FUSED ap branch (bf16 xn out) ----------------
__global__ __launch_bounds__(256, 4) void fused_sage_ap(
    const ushort* __restrict__ xh,
    const ushort* __restrict__ agg,
    const ushort* __restrict__ W0,
    const ushort* __restrict__ W1,
    const float* __restrict__ b0,
    float* __restrict__ outS,
    ushort* __restrict__ outX) {
    constexpr int LROW = 72;
    __shared__ ushort h1s[16 * LROW];
    int wv = threadIdx.x >> 6;
    int lane = threadIdx.x & 63;
    int lrow = lane & 15;
    int koff = (lane >> 4) * 8;
    int crow = (lane >> 4) * 4;
    int row0 = blockIdx.x * 16;

    {
        const size_t aoff = (size_t)(row0 + lrow) * 64 + koff;
        short8 aF[4];
#pragma unroll
        for (int kk = 0; kk < 2; ++kk) {
            aF[kk]     = *(const short8*)(xh + aoff + kk * 32);
            aF[2 + kk] = *(const short8*)(agg + aoff + kk * 32);
        }
        f32x4 acc = {};
#pragma unroll
        for (int kk = 0; kk < 4; ++kk) {
            short8 b = *(const short8*)(W0 + (size_t)(wv * 16 + lrow) * 128 + kk * 32 + koff);
            acc = __builtin_amdgcn_mfma_f32_16x16x32_bf16(aF[kk], b, acc, 0, 0, 0);
        }
        float bb = b0[wv * 16 + lrow];
#pragma unroll
        for (int r = 0; r < 4; ++r) {
            h1s[(crow + r) * LROW + wv * 16 + lrow] = f2bf(fmaxf(acc[r] + bb, 0.0f));
        }
    }
    __syncthreads();
    {
        f32x4 C2[2] = {};
#pragma unroll
        for (int kc = 0; kc < 2; ++kc) {
            short8 a = *(const short8*)&h1s[lrow * LROW + kc * 32 + koff];
#pragma unroll
            for (int c = 0; c < 2; ++c) {
                short8 b = *(const short8*)(W1 + (size_t)(wv * 32 + c * 16 + lrow) * 64 + kc * 32 + koff);
                C2[c] = __builtin_amdgcn_mfma_f32_16x16x32_bf16(a, b, C2[c], 0, 0, 0);
            }
        }
#pragma unroll
        for (int c = 0; c < 2; ++c) {
            int col = wv * 32 + c * 16 + lrow;
#pragma unroll
            for (int r = 0; r < 4; ++r) {
                int row = row0 + crow + r;
                if (row < NN) {
                    if (col < 64) outS[(size_t)row * 64 + col] = C2[c][r];
                    else outX[(size_t)row * 64 + (col - 64)] = f2bf(C2[c][r]);
                }
            }
        }
    }
}

// ---------------- attention reduction ----------------
__global__ __launch_bounds__(256) void att_stage1(const float* __restrict__ pr,
                                                  const float* __restrict__ cc,
                                                  const float* __restrict__ ap,
                                                  const float* __restrict__ attW,
                                                  const float* __restrict__ attb,
                                                  float2* __restrict__ partial) {
    __shared__ float red[8];
    int lane = threadIdx.x & 63;
    int wv = threadIdx.x >> 6;
    int gw = blockIdx.x * 4 + wv;
    const int nwaves = ATT_BLOCKS * 4;
    float b = attb[lane];
    float c0 = 0.f, c1 = 0.f;
    for (int n = gw; n < NN; n += nwaves) {
        float p0 = 0.f, p1 = 0.f;
        for (int k = 0; k < DD; ++k) {
            float w = attW[k * DD + lane];
            p0 = fmaf(pr[n * DD + k], w, p0);
            p1 = fmaf(cc[n * DD + k], w, p1);
        }
        float a = ap[n * DD + lane];
        c0 += a * tanhf(p0 + b);
        c1 += a * tanhf(p1 + b);
    }
#pragma unroll
    for (int off = 32; off; off >>= 1) {
        c0 += __shfl_xor(c0, off);
        c1 += __shfl_xor(c1, off);
    }
    if (lane == 0) { red[wv * 2] = c0; red[wv * 2 + 1] = c1; }
    __syncthreads();
    if (threadIdx.x == 0) {
        partial[blockIdx.x] = make_float2(red[0] + red[2] + red[4] + red[6],
                                          red[1] + red[3] + red[5] + red[7]);
    }
}

__global__ __launch_bounds__(64) void att_stage2(const float2* __restrict__ partial,
                                                 float* __restrict__ w_acc) {
    int lane = threadIdx.x;
    float s0 = 0.f, s1 = 0.f;
    for (int i = lane; i < ATT_BLOCKS; i += 64) {
        float2 p = partial[i];
        s0 += p.x; s1 += p.y;
    }
#pragma unroll
    for (int off = 32; off; off >>= 1) {
        s0 += __shfl_xor(s0, off);
        s1 += __shfl_xor(s1, off);
    }
    if (lane == 0) { w_acc[0] = s0; w_acc[1] = s1; }
}

// ---------------- final (in-place on pr=out) ----------------
__global__ __launch_bounds__(256) void final_kernel(float* __restrict__ pr_out,
                                                    const float* __restrict__ cc,
                                                    const float* __restrict__ w_acc) {
    int t = blockIdx.x * blockDim.x + threadIdx.x;
    if (t >= NN * DD) return;
    float w0 = w_acc[0] * (1.0f / NN);
    float w1 = w_acc[1] * (1.0f / NN);
    float m = fmaxf(w0, w1);
    float e0 = __expf(w0 - m), e1 = __expf(w1 - m);
    float inv = 1.0f / (e0 + e1);
    pr_out[t] = (e0 * pr_out[t] + e1 * cc[t]) * inv;
}

extern "C" void kernel_launch(void* const* d_in, const int* in_sizes, int n_in,
                              void* d_out, int out_size, void* d_ws, size_t ws_size,
                              hipStream_t stream) {
    const float* k_emb  = (const float*)d_in[0];
    const int*   pr_src = (const int*)d_in[1];
    const int*   pr_dst = (const int*)d_in[2];
    const float* pr_ew  = (const float*)d_in[3];
    const int*   cc_src = (const int*)d_in[4];
    const int*   cc_dst = (const int*)d_in[5];
    const float* cc_ew  = (const float*)d_in[6];
    const int*   sps_src = (const int*)d_in[7];
    const int*   sps_dst = (const int*)d_in[8];
    const float* pr_Ws0 = (const float*)d_in[9];
    const float* pr_Wn0 = (const float*)d_in[10];
    const float* pr_b0  = (const float*)d_in[11];
    const float* pr_Ws1 = (const float*)d_in[12];
    const float* pr_Wn1 = (const float*)d_in[13];
    const float* pr_b1  = (const float*)d_in[14];
    const float* cc_Ws0 = (const float*)d_in[15];
    const float* cc_Wn0 = (const float*)d_in[16];
    const float* cc_b0  = (const float*)d_in[17];
    const float* cc_Ws1 = (const float*)d_in[18];
    const float* cc_Wn1 = (const float*)d_in[19];
    const float* cc_b1  = (const float*)d_in[20];
    const float* ap_Ws0 = (const float*)d_in[21];
    const float* ap_Wn0 = (const float*)d_in[22];
    const float* ap_b0  = (const float*)d_in[23];
    const float* ap_Ws1 = (const float*)d_in[24];
    const float* ap_Wn1 = (const float*)d_in[25];
    const float* ap_b1  = (const float*)d_in[26];
    const float* att_W  = (const float*)d_in[27];
    const float* att_b  = (const float*)d_in[28];
    float* out = (float*)d_out;

    // ---- workspace layout (256B-aligned) ----
    char* base = (char*)d_ws;
    size_t off = 0;
    auto alloc = [&](size_t bytes) -> void* {
        void* p = base + off;
        off = (off + bytes + 255) & ~(size_t)255;
        return p;
    };
    float*  invd   = (float*)alloc((size_t)3 * NN * 4);
    int*    cnt    = (int*)alloc((size_t)ZERO_N * 4);  // cnt + ccur, zeroed in pack_all
    int*    ccur   = cnt + 3 * NN;
    int*    rowptr = (int*)alloc((size_t)3 * (NN + 1) * 4);
    uint*   edge_s = (uint*)alloc((size_t)2 * EE * 4);
    ushort* src_s2 = (ushort*)alloc((size_t)EE * 2);
    uint*   ce     = (uint*)alloc((size_t)3 * EE * 4);
    ushort* cd     = (ushort*)alloc((size_t)3 * EE * 2);
    float*  w_acc  = (float*)alloc(64);
    float2* att_partial = (float2*)alloc(ATT_BLOCKS * 8);
    ushort* xnh    = (ushort*)alloc((size_t)3 * NP * DD * 2);
    float*  out_cc = (float*)alloc((size_t)NN * DD * 4);
    float*  out_ap = (float*)alloc((size_t)NN * DD * 4);
    ushort* xh     = (ushort*)alloc((size_t)NP * DD * 2);
    ushort* aggh   = (ushort*)alloc((size_t)3 * NP * DD * 2);
    ushort* W0h_pr = (ushort*)alloc(512 * 128 * 2);
    ushort* W0h_cc = (ushort*)alloc(512 * 128 * 2);
    ushort* W0h_ap = (ushort*)alloc(64 * 128 * 2);
    ushort* W1h_pr = (ushort*)alloc(128 * 512 * 2);
    ushort* W1h_cc = (ushort*)alloc(128 * 512 * 2);
    ushort* W1h_ap = (ushort*)alloc(128 * 64 * 2);
    float*  out_pr = out;

    const int TB = 256;
    const int blocks_ND = (NN * DD) / TB;          // 5000
    const int blocks_pull = (3 * NN * 64) / TB;    // 15000 (1 wave/node)
    const int NBLK64 = NP / 64;                    // 313
    const int blocks_hist = 3 * ((EE + 1023) / 1024);  // 939

    // ---- prologue ----
    pack_all<<<1088 + ZERO_BLOCKS + blocks_ND, TB, 0, stream>>>(
        pr_Ws0, pr_Wn0, cc_Ws0, cc_Wn0, pr_Ws1, pr_Wn1, cc_Ws1, cc_Wn1,
        ap_Ws0, ap_Wn0, ap_Ws1, ap_Wn1, k_emb,
        W0h_pr, W0h_cc, W1h_pr, W1h_cc, W0h_ap, W1h_ap, xh, cnt);

    hist3<<<blocks_hist, TB, 0, stream>>>(pr_dst, cc_dst, sps_dst, cnt);
    scan_kernel<<<3, 1024, 0, stream>>>(cnt, rowptr, invd);
    bucket_coarse<<<3 * B1_BLOCKS, TB, 0, stream>>>(pr_src, pr_dst, pr_ew,
                                                    cc_src, cc_dst, cc_ew,
                                                    sps_src, sps_dst,
                                                    rowptr, ccur, ce, cd);
    bucket_fine<<<3 * CB, TB, 0, stream>>>(rowptr, ce, cd, edge_s, src_s2);

    // ---- layer-0 aggregation (quarter-wave bf16 gather) ----
    pull_cast3<<<blocks_pull, TB, 0, stream>>>(xh, rowptr, edge_s, src_s2, invd, aggh);

    // ---- fused layer0+layer1 ----
    fused_sage4<<<2 * NBLK64, 512, 0, stream>>>(
        xh, aggh,
        W0h_pr, W1h_pr, W0h_cc, W1h_cc,
        pr_b0, cc_b0, out_pr, out_cc, xnh, NBLK64);
    fused_sage_ap<<<NP / 16, 256, 0, stream>>>(
        xh, aggh + (size_t)2 * NP * 64,
        W0h_ap, W1h_ap, ap_b0, out_ap, xnh + (size_t)2 * NP * 64);

    // ---- layer-1 aggregation + combine (quarter-wave bf16 gather) ----
    pull_combine3<<<blocks_pull, TB, 0, stream>>>(xnh, rowptr, edge_s, src_s2, invd,
                                                  pr_b1, cc_b1, ap_b1,
                                                  out_pr, out_cc, out_ap);

    // ---- attention fusion ----
    att_stage1<<<ATT_BLOCKS, TB, 0, stream>>>(out_pr, out_cc, out_ap, att_W, att_b, att_partial);
    att_stage2<<<1, 64, 0, stream>>>(att_partial, w_acc);
    final_kernel<<<blocks_ND, TB, 0, stream>>>(out_pr, out_cc, w_acc);
}